// Round 1
// 4264.868 us; speedup vs baseline: 1.5654x; 1.5654x over previous
//
#include <hip/hip_runtime.h>
#include <hip/hip_bf16.h>
#include <stdint.h>

// CTRNN: B=64, T=1000, N_IN=128, N_REC=1024, N_OUT=64
// Persistent-group design, round 3 (counter-free tagged exchange):
//   grid = 256 WGs x 256 threads. group g = bid&3 (4 groups x 16 batches),
//   member m = bid>>2 (64 members, each owns 16 neurons and output o=m).
//   Weff slab (16x1024 bf16, swizzled) + Wahx slab + Wyh row live in LDS.
//   h exchange: each packed 32b h-word carries a PHASE TAG in bit31 (sign of
//   the high bf16; h=retanh>=0 so sign is naturally 0). Producer tags with
//   ((t+1)>>1)&1; consumer polls its own fragment loads until all tags match
//   (t>>1)&1, then masks tags off. The successful poll IS the data load.
//   Removes the 256-way contended atomic counter + RMW serialization + poll
//   round-trip that dominated the previous 6.7us/step critical path.
//   Safety: slot parity (t&1) + phase parity ((t>>1)&1) give period-4
//   disambiguation; transitive dependency (consumer at t => producers wrote
//   h(t) => producers observed h(t-2) at LLC) bounds slot content to
//   {h(t), h(t-2)} -> no false accept. hbuf pre-poisoned 0xFF (tag=1).

#define B_    64
#define T_    1000
#define NIN   128
#define NREC  1024
#define NOUT  64
#define GROUPS  4
#define MEMBERS 64
#define BPG   16   // batches per group
#define NSL   16   // n-slice per member

#define DT    0.1f

typedef short  bf16x8 __attribute__((ext_vector_type(8)));
typedef float  f32x4  __attribute__((ext_vector_type(4)));

#define SCOPE __HIP_MEMORY_SCOPE_AGENT

// ws layout
#define XB_OFF     0
#define XB_BYTES   (B_ * T_ * NIN * 2)                      // 16,384,000 (16B aligned)
#define HBUF_OFF   (XB_OFF + XB_BYTES)
#define HBUF_BYTES (GROUPS * 2 * BPG * NREC * 2)            // 262,144

#define TAGMASK 0x8000000080000000ull

union U16B { unsigned long long q[2]; bf16x8 s; };

__device__ __forceinline__ unsigned short f2bf(float f) {
    unsigned u = __float_as_uint(f);
    unsigned r = u + 0x7fffu + ((u >> 16) & 1u);
    return (unsigned short)(r >> 16);
}
__device__ __forceinline__ unsigned pack2(float lo, float hi) {
    return (unsigned)f2bf(lo) | ((unsigned)f2bf(hi) << 16);
}

__global__ void cast_x_kernel(const float* __restrict__ x, unsigned short* __restrict__ xb, int n4) {
    int i = blockIdx.x * blockDim.x + threadIdx.x;
    int stride = gridDim.x * blockDim.x;
    for (; i < n4; i += stride) {
        float4 v = ((const float4*)x)[i];
        unsigned lo = pack2(v.x, v.y);
        unsigned hi = pack2(v.z, v.w);
        ((uint2*)xb)[i] = make_uint2(lo, hi);
    }
}

__global__ __launch_bounds__(256, 1)
void rnn_main(const float* __restrict__ Wahx, const float* __restrict__ Wahh,
              const float* __restrict__ Wyh,  const float* __restrict__ bah,
              const float* __restrict__ by,   const float* __restrict__ ah0,
              const float* __restrict__ mask,
              const unsigned short* __restrict__ xb,
              unsigned short* __restrict__ hbuf,
              float* __restrict__ y)
{
    __shared__ unsigned short weff[NSL * NREC];   // 32 KB, swizzled rows
    __shared__ unsigned short wahxs[NSL * NIN];   // 4 KB, swizzled rows
    __shared__ unsigned short wyhs[NREC];         // 2 KB, single row o=m
    __shared__ float red[4][2][64][4];            // 8 KB: [wave][rec/y][lane][reg]

    const int tid  = threadIdx.x;
    const int w    = tid >> 6;        // wave 0..3 (K-range w*256..)
    const int lane = tid & 63;
    const int bid  = blockIdx.x;
    const int g    = bid & 3;         // group
    const int m    = bid >> 2;        // member 0..63

    // ---- init: build LDS slabs ----
    for (int cc = 0; cc < 8; ++cc) {
        int cid = cc * 256 + tid;           // 2048 chunks of 8
        int rl = cid >> 7;                  // local row 0..15
        int k  = (cid & 127) * 8;
        const float* wr = Wahh + (m * NSL + rl) * NREC + k;
        const float* mr = mask + (m * NSL + rl) * NREC + k;
        float4 a0 = *(const float4*)wr;     float4 a1 = *(const float4*)(wr + 4);
        float4 m0 = *(const float4*)mr;     float4 m1 = *(const float4*)(mr + 4);
        uint4 pk;
        pk.x = pack2(fabsf(a0.x) * m0.x, fabsf(a0.y) * m0.y);
        pk.y = pack2(fabsf(a0.z) * m0.z, fabsf(a0.w) * m0.w);
        pk.z = pack2(fabsf(a1.x) * m1.x, fabsf(a1.y) * m1.y);
        pk.w = pack2(fabsf(a1.z) * m1.z, fabsf(a1.w) * m1.w);
        int byte = (rl * 2048 + k * 2) ^ ((rl & 7) << 4);
        *(uint4*)((char*)weff + byte) = pk;
    }
    {
        int rl = tid >> 4;
        int k  = (tid & 15) * 8;
        const float* wr = Wahx + (m * NSL + rl) * NIN + k;
        float4 a0 = *(const float4*)wr;  float4 a1 = *(const float4*)(wr + 4);
        uint4 pk;
        pk.x = pack2(a0.x, a0.y); pk.y = pack2(a0.z, a0.w);
        pk.z = pack2(a1.x, a1.y); pk.w = pack2(a1.z, a1.w);
        int byte = (rl * 256 + k * 2) ^ ((rl & 7) << 4);
        *(uint4*)((char*)wahxs + byte) = pk;
    }
    if (tid < 128) {
        int k = tid * 8;
        const float* wr = Wyh + m * NREC + k;
        float4 a0 = *(const float4*)wr;  float4 a1 = *(const float4*)(wr + 4);
        uint4 pk;
        pk.x = pack2(a0.x, a0.y); pk.y = pack2(a0.z, a0.w);
        pk.z = pack2(a1.x, a1.y); pk.w = pack2(a1.z, a1.w);
        *(uint4*)((char*)wyhs + k * 2) = pk;
    }

    // per-thread state: (b_loc, nl)
    const int b_loc = tid >> 4;
    const int nl    = tid & 15;
    const int n_g   = m * NSL + nl;
    float ahv  = ah0[n_g];
    float bahv = bah[n_g];
    float byv  = by[m];

    // h(0) = retanh(ah0) -> hbuf slot 0, tag 0 (natural sign bits)
    {
        float th = tanhf(ahv);
        float h0 = th > 0.f ? th : 0.f;
        unsigned hb = f2bf(h0);
        unsigned nb = __shfl_down(hb, 1);
        if ((nl & 1) == 0) {
            unsigned w32 = hb | (nb << 16);
            int eidx = ((g * 2 + 0) * BPG + b_loc) * NREC + n_g;
            __hip_atomic_store((unsigned*)hbuf + (eidx >> 1), w32, __ATOMIC_RELAXED, SCOPE);
        }
    }
    __syncthreads();   // LDS slabs ready before use

    const int bcol = lane & 15;          // batch col for MFMA, also A row
    const int khi  = (lane >> 4) * 8;    // per-lane k offset within 32-chunk

    for (int t = 0; t <= T_; ++t) {
        // ---- prefetch x fragment (independent of h(t)) ----
        bf16x8 xf, axf;
        if (t < T_) {
            int i = w * 32 + khi;
            xf = *(const bf16x8*)(xb + ((size_t)(g * BPG + bcol) * T_ + t) * NIN + i);
            int byte = (bcol * 256 + i * 2) ^ ((bcol & 7) << 4);
            axf = *(const bf16x8*)((const char*)wahxs + byte);
        }

        // ---- poll-load h(t): all words of this wave's fragment tagged ----
        const int slot = t & 1;
        const unsigned long long want = ((t >> 1) & 1) ? TAGMASK : 0ull;
        unsigned long long* hq =
            (unsigned long long*)(hbuf + ((g * 2 + slot) * BPG + bcol) * NREC);

        U16B u[8];
        for (;;) {
            unsigned long long diff = 0;
            #pragma unroll
            for (int c = 0; c < 8; ++c) {
                int k = w * 256 + c * 32 + khi;
                u[c].q[0] = __hip_atomic_load(hq + (k >> 2),     __ATOMIC_RELAXED, SCOPE);
                u[c].q[1] = __hip_atomic_load(hq + (k >> 2) + 1, __ATOMIC_RELAXED, SCOPE);
                diff |= (u[c].q[0] ^ want) & TAGMASK;
                diff |= (u[c].q[1] ^ want) & TAGMASK;
            }
            if (!__any(diff != 0)) break;
        }
        bf16x8 bfrag[8];
        #pragma unroll
        for (int c = 0; c < 8; ++c) {
            u[c].q[0] &= ~TAGMASK;      // clear tags (real sign bits are 0)
            u[c].q[1] &= ~TAGMASK;
            bfrag[c] = u[c].s;
        }

        f32x4 acc = {0.f, 0.f, 0.f, 0.f};
        if (t < T_) {
            // two independent accumulators halve the serial MFMA dep chain
            f32x4 a0 = {0.f, 0.f, 0.f, 0.f};
            f32x4 a1 = {0.f, 0.f, 0.f, 0.f};
            a0 = __builtin_amdgcn_mfma_f32_16x16x32_bf16(axf, xf, a0, 0, 0, 0);
            #pragma unroll
            for (int c = 0; c < 4; ++c) {
                int k = w * 256 + c * 32 + khi;
                int byte = (bcol * 2048 + k * 2) ^ ((bcol & 7) << 4);
                bf16x8 af = *(const bf16x8*)((const char*)weff + byte);
                a0 = __builtin_amdgcn_mfma_f32_16x16x32_bf16(af, bfrag[c], a0, 0, 0, 0);
            }
            #pragma unroll
            for (int c = 4; c < 8; ++c) {
                int k = w * 256 + c * 32 + khi;
                int byte = (bcol * 2048 + k * 2) ^ ((bcol & 7) << 4);
                bf16x8 af = *(const bf16x8*)((const char*)weff + byte);
                a1 = __builtin_amdgcn_mfma_f32_16x16x32_bf16(af, bfrag[c], a1, 0, 0, 0);
            }
            acc = a0 + a1;
        }

        *(f32x4*)&red[w][0][lane][0] = acc;
        __syncthreads();

        if (t < T_) {
            // D mapping: col = lane&15 (=batch), row = (lane>>4)*4 + reg (=n-local)
            int src = ((nl >> 2) << 4) | b_loc;
            int reg = nl & 3;
            float r = red[0][0][src][reg] + red[1][0][src][reg]
                    + red[2][0][src][reg] + red[3][0][src][reg];
            ahv = 0.9f * ahv + DT * (r + bahv);
            float th = tanhf(ahv);
            float h  = th > 0.f ? th : 0.f;
            unsigned hb = f2bf(h);
            unsigned nb = __shfl_down(hb, 1);
            if ((nl & 1) == 0) {
                unsigned tagw = (unsigned)(((t + 1) >> 1) & 1) << 31;
                unsigned w32 = hb | (nb << 16) | tagw;
                int eidx = ((g * 2 + (slot ^ 1)) * BPG + b_loc) * NREC + n_g;
                __hip_atomic_store((unsigned*)hbuf + (eidx >> 1), w32, __ATOMIC_RELAXED, SCOPE);
            }
            // no waitcnt / no counter post: each word self-announces via its tag
        }

        // ---- y for output step t-1 (off the critical inter-WG chain) ----
        if (t >= 1) {
            f32x4 accy = {0.f, 0.f, 0.f, 0.f};
            #pragma unroll
            for (int c = 0; c < 8; ++c) {
                int k = w * 256 + c * 32 + khi;
                bf16x8 af = *(const bf16x8*)((const char*)wyhs + k * 2);
                accy = __builtin_amdgcn_mfma_f32_16x16x32_bf16(af, bfrag[c], accy, 0, 0, 0);
            }
            *(f32x4*)&red[w][1][lane][0] = accy;
            __syncthreads();
            if (tid < BPG) {
                float yv = red[0][1][tid][0] + red[1][1][tid][0]
                         + red[2][1][tid][0] + red[3][1][tid][0] + byv;
                __builtin_nontemporal_store(yv, &y[((size_t)(g * BPG + tid) * T_ + (t - 1)) * NOUT + m]);
            }
        } else {
            // t==0 has no y-phase barrier; the old global counter transitively
            // ordered own-WG waves here. Order red[][0] reads before t=1 writes.
            __syncthreads();
        }
    }
}

extern "C" void kernel_launch(void* const* d_in, const int* in_sizes, int n_in,
                              void* d_out, int out_size, void* d_ws, size_t ws_size,
                              hipStream_t stream) {
    const float* x    = (const float*)d_in[0];
    const float* Wahx = (const float*)d_in[1];
    const float* Wahh = (const float*)d_in[2];
    const float* Wyh  = (const float*)d_in[3];
    const float* bah  = (const float*)d_in[4];
    const float* by   = (const float*)d_in[5];
    const float* ah0  = (const float*)d_in[6];
    const float* mask = (const float*)d_in[7];
    float* y = (float*)d_out;
    char* ws = (char*)d_ws;
    unsigned short* xb   = (unsigned short*)(ws + XB_OFF);
    unsigned short* hbuf = (unsigned short*)(ws + HBUF_OFF);

    (void)in_sizes; (void)n_in; (void)out_size; (void)ws_size;

    // poison hbuf: all tag bits = 1, so phase-0 consumers (t=0,1) cannot
    // false-accept before the first writes land.
    hipMemsetAsync(hbuf, 0xFF, HBUF_BYTES, stream);
    cast_x_kernel<<<dim3(2048), dim3(256), 0, stream>>>(x, xb, (B_ * T_ * NIN) / 4);
    rnn_main<<<dim3(GROUPS * MEMBERS), dim3(256), 0, stream>>>(
        Wahx, Wahh, Wyh, bah, by, ah0, mask, xb, hbuf, y);
}

// Round 2
// 3503.460 us; speedup vs baseline: 1.9056x; 1.2173x over previous
//
#include <hip/hip_runtime.h>
#include <hip/hip_bf16.h>
#include <stdint.h>

// CTRNN: B=64, T=1000, N_IN=128, N_REC=1024, N_OUT=64
// Persistent-group design, round 4 (per-producer flag release protocol):
//   grid = 256 WGs x 256 threads. group g = bid&3 (4 groups x 16 batches),
//   member m = bid>>2 (64 members, each owns 16 neurons and output o=m).
//   Weff slab (16x1024 bf16, swizzled) + Wahx slab + Wyh row live in LDS.
//   h exchange: producer WAVE (member m, wave pw stores batches 4pw..4pw+3)
//   stores its h words, s_waitcnt vmcnt(0) (stores acked at coherence point),
//   then lane0 posts a MONOTONIC flag = t+1 on its own 64B-strided line.
//   Consumer wave: lane l polls flag[member w*16 + (l>>2)][wave l&3] — one
//   4B load per lane per round (256B/wave vs 8KB/wave for the round-3 tag
//   poll => ~32x less LLC poll traffic; polling no longer congests the
//   fabric the producers' stores traverse). Data then loaded exactly once.
//   Slot reuse (period 2) safe: producer overwrites slot s with h(t+2) only
//   after observing flags >= t+2, which requires every consumer to have
//   READ h(t) (their reads feed the h(t+1) they posted). Monotonic flags
//   remove parity ambiguity; no tag bits, no poisoning.

#define B_    64
#define T_    1000
#define NIN   128
#define NREC  1024
#define NOUT  64
#define GROUPS  4
#define MEMBERS 64
#define BPG   16   // batches per group
#define NSL   16   // n-slice per member

#define DT    0.1f

typedef short  bf16x8 __attribute__((ext_vector_type(8)));
typedef float  f32x4  __attribute__((ext_vector_type(4)));

#define SCOPE __HIP_MEMORY_SCOPE_AGENT

// ws layout
#define XB_OFF     0
#define XB_BYTES   (B_ * T_ * NIN * 2)                      // 16,384,000 (64B aligned)
#define FLG_OFF    (XB_OFF + XB_BYTES)
#define FLG_BYTES  (GROUPS * MEMBERS * 4 * 64)              // 65,536 (64B/flag line)
#define HBUF_OFF   (FLG_OFF + FLG_BYTES)
#define HBUF_BYTES (GROUPS * 2 * BPG * NREC * 2)            // 262,144

union U16B { unsigned long long q[2]; bf16x8 s; };

__device__ __forceinline__ unsigned short f2bf(float f) {
    unsigned u = __float_as_uint(f);
    unsigned r = u + 0x7fffu + ((u >> 16) & 1u);
    return (unsigned short)(r >> 16);
}
__device__ __forceinline__ unsigned pack2(float lo, float hi) {
    return (unsigned)f2bf(lo) | ((unsigned)f2bf(hi) << 16);
}

__global__ void cast_x_kernel(const float* __restrict__ x, unsigned short* __restrict__ xb, int n4) {
    int i = blockIdx.x * blockDim.x + threadIdx.x;
    int stride = gridDim.x * blockDim.x;
    for (; i < n4; i += stride) {
        float4 v = ((const float4*)x)[i];
        unsigned lo = pack2(v.x, v.y);
        unsigned hi = pack2(v.z, v.w);
        ((uint2*)xb)[i] = make_uint2(lo, hi);
    }
}

__global__ __launch_bounds__(256, 1)
void rnn_main(const float* __restrict__ Wahx, const float* __restrict__ Wahh,
              const float* __restrict__ Wyh,  const float* __restrict__ bah,
              const float* __restrict__ by,   const float* __restrict__ ah0,
              const float* __restrict__ mask,
              const unsigned short* __restrict__ xb,
              unsigned* __restrict__ flags,
              unsigned short* __restrict__ hbuf,
              float* __restrict__ y)
{
    __shared__ unsigned short weff[NSL * NREC];   // 32 KB, swizzled rows
    __shared__ unsigned short wahxs[NSL * NIN];   // 4 KB, swizzled rows
    __shared__ unsigned short wyhs[NREC];         // 2 KB, single row o=m
    __shared__ float red[4][2][64][4];            // 8 KB: [wave][rec/y][lane][reg]

    const int tid  = threadIdx.x;
    const int w    = tid >> 6;        // wave 0..3 (K-range w*256..)
    const int lane = tid & 63;
    const int bid  = blockIdx.x;
    const int g    = bid & 3;         // group
    const int m    = bid >> 2;        // member 0..63

    // ---- init: build LDS slabs ----
    for (int cc = 0; cc < 8; ++cc) {
        int cid = cc * 256 + tid;           // 2048 chunks of 8
        int rl = cid >> 7;                  // local row 0..15
        int k  = (cid & 127) * 8;
        const float* wr = Wahh + (m * NSL + rl) * NREC + k;
        const float* mr = mask + (m * NSL + rl) * NREC + k;
        float4 a0 = *(const float4*)wr;     float4 a1 = *(const float4*)(wr + 4);
        float4 m0 = *(const float4*)mr;     float4 m1 = *(const float4*)(mr + 4);
        uint4 pk;
        pk.x = pack2(fabsf(a0.x) * m0.x, fabsf(a0.y) * m0.y);
        pk.y = pack2(fabsf(a0.z) * m0.z, fabsf(a0.w) * m0.w);
        pk.z = pack2(fabsf(a1.x) * m1.x, fabsf(a1.y) * m1.y);
        pk.w = pack2(fabsf(a1.z) * m1.z, fabsf(a1.w) * m1.w);
        int byte = (rl * 2048 + k * 2) ^ ((rl & 7) << 4);
        *(uint4*)((char*)weff + byte) = pk;
    }
    {
        int rl = tid >> 4;
        int k  = (tid & 15) * 8;
        const float* wr = Wahx + (m * NSL + rl) * NIN + k;
        float4 a0 = *(const float4*)wr;  float4 a1 = *(const float4*)(wr + 4);
        uint4 pk;
        pk.x = pack2(a0.x, a0.y); pk.y = pack2(a0.z, a0.w);
        pk.z = pack2(a1.x, a1.y); pk.w = pack2(a1.z, a1.w);
        int byte = (rl * 256 + k * 2) ^ ((rl & 7) << 4);
        *(uint4*)((char*)wahxs + byte) = pk;
    }
    if (tid < 128) {
        int k = tid * 8;
        const float* wr = Wyh + m * NREC + k;
        float4 a0 = *(const float4*)wr;  float4 a1 = *(const float4*)(wr + 4);
        uint4 pk;
        pk.x = pack2(a0.x, a0.y); pk.y = pack2(a0.z, a0.w);
        pk.z = pack2(a1.x, a1.y); pk.w = pack2(a1.z, a1.w);
        *(uint4*)((char*)wyhs + k * 2) = pk;
    }

    // per-thread state: (b_loc, nl)
    const int b_loc = tid >> 4;
    const int nl    = tid & 15;
    const int n_g   = m * NSL + nl;
    float ahv  = ah0[n_g];
    float bahv = bah[n_g];
    float byv  = by[m];

    // this producer-wave's flag line (member m, wave w)
    unsigned* myflag = flags + (((size_t)g * MEMBERS + m) * 4 + w) * 16;
    // consumer poll target: lane l watches (member w*16 + (l>>2), wave l&3)
    unsigned* pollp = flags + (((size_t)g * MEMBERS + (w * 16 + (lane >> 2))) * 4 + (lane & 3)) * 16;

    // h(0) = retanh(ah0) -> hbuf slot 0; release with flag=1
    {
        float th = tanhf(ahv);
        float h0 = th > 0.f ? th : 0.f;
        unsigned hb = f2bf(h0);
        unsigned nb = __shfl_down(hb, 1);
        if ((nl & 1) == 0) {
            unsigned w32 = hb | (nb << 16);
            int eidx = ((g * 2 + 0) * BPG + b_loc) * NREC + n_g;
            __hip_atomic_store((unsigned*)hbuf + (eidx >> 1), w32, __ATOMIC_RELAXED, SCOPE);
        }
        asm volatile("s_waitcnt vmcnt(0)" ::: "memory");   // h(0) acked at coherence point
        if (lane == 0)
            __hip_atomic_store(myflag, 1u, __ATOMIC_RELAXED, SCOPE);
    }
    __syncthreads();   // LDS slabs ready before use

    const int bcol = lane & 15;          // batch col for MFMA, also A row
    const int khi  = (lane >> 4) * 8;    // per-lane k offset within 32-chunk

    for (int t = 0; t <= T_; ++t) {
        // ---- prefetch x fragment (independent of h(t)) ----
        bf16x8 xf, axf;
        if (t < T_) {
            int i = w * 32 + khi;
            xf = *(const bf16x8*)(xb + ((size_t)(g * BPG + bcol) * T_ + t) * NIN + i);
            int byte = (bcol * 256 + i * 2) ^ ((bcol & 7) << 4);
            axf = *(const bf16x8*)((const char*)wahxs + byte);
        }

        // ---- acquire h(t): poll 64 per-producer flags, one per lane ----
        {
            const unsigned want = (unsigned)(t + 1);   // flag >= t+1 <=> h(t) visible
            unsigned v;
            do {
                v = __hip_atomic_load(pollp, __ATOMIC_RELAXED, SCOPE);
            } while (__any(v < want));
        }
        asm volatile("" ::: "memory");   // keep h data loads below the poll

        // ---- load h(t) exactly once (coherent, untagged) ----
        const int slot = t & 1;
        unsigned long long* hq =
            (unsigned long long*)(hbuf + ((g * 2 + slot) * BPG + bcol) * NREC);
        bf16x8 bfrag[8];
        #pragma unroll
        for (int c = 0; c < 8; ++c) {
            int k = w * 256 + c * 32 + khi;
            U16B u;
            u.q[0] = __hip_atomic_load(hq + (k >> 2),     __ATOMIC_RELAXED, SCOPE);
            u.q[1] = __hip_atomic_load(hq + (k >> 2) + 1, __ATOMIC_RELAXED, SCOPE);
            bfrag[c] = u.s;
        }

        f32x4 acc = {0.f, 0.f, 0.f, 0.f};
        if (t < T_) {
            // two independent accumulators halve the serial MFMA dep chain
            f32x4 a0 = {0.f, 0.f, 0.f, 0.f};
            f32x4 a1 = {0.f, 0.f, 0.f, 0.f};
            a0 = __builtin_amdgcn_mfma_f32_16x16x32_bf16(axf, xf, a0, 0, 0, 0);
            #pragma unroll
            for (int c = 0; c < 4; ++c) {
                int k = w * 256 + c * 32 + khi;
                int byte = (bcol * 2048 + k * 2) ^ ((bcol & 7) << 4);
                bf16x8 af = *(const bf16x8*)((const char*)weff + byte);
                a0 = __builtin_amdgcn_mfma_f32_16x16x32_bf16(af, bfrag[c], a0, 0, 0, 0);
            }
            #pragma unroll
            for (int c = 4; c < 8; ++c) {
                int k = w * 256 + c * 32 + khi;
                int byte = (bcol * 2048 + k * 2) ^ ((bcol & 7) << 4);
                bf16x8 af = *(const bf16x8*)((const char*)weff + byte);
                a1 = __builtin_amdgcn_mfma_f32_16x16x32_bf16(af, bfrag[c], a1, 0, 0, 0);
            }
            acc = a0 + a1;
        }

        *(f32x4*)&red[w][0][lane][0] = acc;
        __syncthreads();

        if (t < T_) {
            // D mapping: col = lane&15 (=batch), row = (lane>>4)*4 + reg (=n-local)
            int src = ((nl >> 2) << 4) | b_loc;
            int reg = nl & 3;
            float r = red[0][0][src][reg] + red[1][0][src][reg]
                    + red[2][0][src][reg] + red[3][0][src][reg];
            ahv = 0.9f * ahv + DT * (r + bahv);
            float th = tanhf(ahv);
            float h  = th > 0.f ? th : 0.f;
            unsigned hb = f2bf(h);
            unsigned nb = __shfl_down(hb, 1);
            if ((nl & 1) == 0) {
                unsigned w32 = hb | (nb << 16);
                int eidx = ((g * 2 + (slot ^ 1)) * BPG + b_loc) * NREC + n_g;
                __hip_atomic_store((unsigned*)hbuf + (eidx >> 1), w32, __ATOMIC_RELAXED, SCOPE);
            }
            // release h(t+1): ack this wave's stores, then post monotonic flag
            asm volatile("s_waitcnt vmcnt(0)" ::: "memory");
            if (lane == 0)
                __hip_atomic_store(myflag, (unsigned)(t + 2), __ATOMIC_RELAXED, SCOPE);
        }

        // ---- y for output step t-1 (off the critical inter-WG chain) ----
        if (t >= 1) {
            f32x4 accy = {0.f, 0.f, 0.f, 0.f};
            #pragma unroll
            for (int c = 0; c < 8; ++c) {
                int k = w * 256 + c * 32 + khi;
                bf16x8 af = *(const bf16x8*)((const char*)wyhs + k * 2);
                accy = __builtin_amdgcn_mfma_f32_16x16x32_bf16(af, bfrag[c], accy, 0, 0, 0);
            }
            *(f32x4*)&red[w][1][lane][0] = accy;
            __syncthreads();
            if (tid < BPG) {
                float yv = red[0][1][tid][0] + red[1][1][tid][0]
                         + red[2][1][tid][0] + red[3][1][tid][0] + byv;
                __builtin_nontemporal_store(yv, &y[((size_t)(g * BPG + tid) * T_ + (t - 1)) * NOUT + m]);
            }
        } else {
            // t==0 has no y-phase barrier; order red[][0] reads before t=1 writes.
            __syncthreads();
        }
    }
}

extern "C" void kernel_launch(void* const* d_in, const int* in_sizes, int n_in,
                              void* d_out, int out_size, void* d_ws, size_t ws_size,
                              hipStream_t stream) {
    const float* x    = (const float*)d_in[0];
    const float* Wahx = (const float*)d_in[1];
    const float* Wahh = (const float*)d_in[2];
    const float* Wyh  = (const float*)d_in[3];
    const float* bah  = (const float*)d_in[4];
    const float* by   = (const float*)d_in[5];
    const float* ah0  = (const float*)d_in[6];
    const float* mask = (const float*)d_in[7];
    float* y = (float*)d_out;
    char* ws = (char*)d_ws;
    unsigned short* xb   = (unsigned short*)(ws + XB_OFF);
    unsigned*       flags = (unsigned*)(ws + FLG_OFF);
    unsigned short* hbuf = (unsigned short*)(ws + HBUF_OFF);

    (void)in_sizes; (void)n_in; (void)out_size; (void)ws_size;

    // flags must start at 0 (monotonic step counters)
    hipMemsetAsync(flags, 0, FLG_BYTES, stream);
    cast_x_kernel<<<dim3(2048), dim3(256), 0, stream>>>(x, xb, (B_ * T_ * NIN) / 4);
    rnn_main<<<dim3(GROUPS * MEMBERS), dim3(256), 0, stream>>>(
        Wahx, Wahh, Wyh, bah, by, ah0, mask, xb, flags, hbuf, y);
}

// Round 4
// 3174.992 us; speedup vs baseline: 2.1027x; 1.1035x over previous
//
#include <hip/hip_runtime.h>
#include <hip/hip_bf16.h>
#include <stdint.h>

// CTRNN: B=64, T=1000, N_IN=128, N_REC=1024, N_OUT=64
// Persistent-group design, round 6 (tagged exchange + per-chunk retry):
//   grid = 256 WGs x 256 threads. group g = bid&3 (4 groups x 16 batches),
//   member m = bid>>2 (64 members, each owns 16 neurons and output o=m).
//   Weff slab (16x1024 bf16, swizzled) + Wahx slab + Wyh row live in LDS.
//   h exchange: each packed 32b h-word carries a PHASE TAG in bit31 (sign of
//   the high bf16; h=retanh>=0 so sign is naturally 0). Producer tags with
//   ((t+1)>>1)&1 and just STORES — no vmcnt ack, no flag (the tag rides with
//   the data, so the successful consumer poll IS the fetch: one LLC hop
//   replaces round-4's store-ack + flag-visible + data-fetch chain).
//   Round-3's failure mode (full 8KB/wave reload every poll round -> ~8MB/
//   round chip-wide -> LLC congestion, 24.7ms outlier) is fixed by PER-CHUNK
//   RETRY: each lane keeps an 8-bit pending mask and reloads only chunks
//   whose tags failed, with s_sleep backoff between rounds. Steady-state
//   poll traffic ~1.2x data volume.
//   Safety (verified in round 3, unchanged): slot parity (t&1) + phase
//   parity ((t>>1)&1) give period-4 disambiguation; consumer at t implies
//   h(t-2) reached LLC (it read it), so per-address coherence order bounds
//   slot content to {h(t-2): tag mismatch, h(t): tag match}. A validated
//   word's snapshot is final: h(t+2) cannot be written before this consumer
//   posts h(t+1). hbuf pre-poisoned 0xFF (tag=1) protects t=0/t=1.

#define B_    64
#define T_    1000
#define NIN   128
#define NREC  1024
#define NOUT  64
#define GROUPS  4
#define MEMBERS 64
#define BPG   16   // batches per group
#define NSL   16   // n-slice per member

#define DT    0.1f

typedef short  bf16x8 __attribute__((ext_vector_type(8)));
typedef float  f32x4  __attribute__((ext_vector_type(4)));

#define SCOPE __HIP_MEMORY_SCOPE_AGENT

// ws layout
#define XB_OFF     0
#define XB_BYTES   (B_ * T_ * NIN * 2)                      // 16,384,000 (16B aligned)
#define HBUF_OFF   (XB_OFF + XB_BYTES)
#define HBUF_BYTES (GROUPS * 2 * BPG * NREC * 2)            // 262,144

#define TAGMASK 0x8000000080000000ull

union U16B { unsigned long long q[2]; bf16x8 s; };

__device__ __forceinline__ unsigned short f2bf(float f) {
    unsigned u = __float_as_uint(f);
    unsigned r = u + 0x7fffu + ((u >> 16) & 1u);
    return (unsigned short)(r >> 16);
}
__device__ __forceinline__ unsigned pack2(float lo, float hi) {
    return (unsigned)f2bf(lo) | ((unsigned)f2bf(hi) << 16);
}

__global__ void cast_x_kernel(const float* __restrict__ x, unsigned short* __restrict__ xb, int n4) {
    int i = blockIdx.x * blockDim.x + threadIdx.x;
    int stride = gridDim.x * blockDim.x;
    for (; i < n4; i += stride) {
        float4 v = ((const float4*)x)[i];
        unsigned lo = pack2(v.x, v.y);
        unsigned hi = pack2(v.z, v.w);
        ((uint2*)xb)[i] = make_uint2(lo, hi);
    }
}

__global__ __launch_bounds__(256, 1)
void rnn_main(const float* __restrict__ Wahx, const float* __restrict__ Wahh,
              const float* __restrict__ Wyh,  const float* __restrict__ bah,
              const float* __restrict__ by,   const float* __restrict__ ah0,
              const float* __restrict__ mask,
              const unsigned short* __restrict__ xb,
              unsigned short* __restrict__ hbuf,
              float* __restrict__ y)
{
    __shared__ unsigned short weff[NSL * NREC];   // 32 KB, swizzled rows
    __shared__ unsigned short wahxs[NSL * NIN];   // 4 KB, swizzled rows
    __shared__ unsigned short wyhs[NREC];         // 2 KB, single row o=m
    __shared__ float red[4][2][64][4];            // 8 KB: [wave][rec/y][lane][reg]

    const int tid  = threadIdx.x;
    const int w    = tid >> 6;        // wave 0..3 (K-range w*256..)
    const int lane = tid & 63;
    const int bid  = blockIdx.x;
    const int g    = bid & 3;         // group
    const int m    = bid >> 2;        // member 0..63

    // ---- init: build LDS slabs ----
    for (int cc = 0; cc < 8; ++cc) {
        int cid = cc * 256 + tid;           // 2048 chunks of 8
        int rl = cid >> 7;                  // local row 0..15
        int k  = (cid & 127) * 8;
        const float* wr = Wahh + (m * NSL + rl) * NREC + k;
        const float* mr = mask + (m * NSL + rl) * NREC + k;
        float4 a0 = *(const float4*)wr;     float4 a1 = *(const float4*)(wr + 4);
        float4 m0 = *(const float4*)mr;     float4 m1 = *(const float4*)(mr + 4);
        uint4 pk;
        pk.x = pack2(fabsf(a0.x) * m0.x, fabsf(a0.y) * m0.y);
        pk.y = pack2(fabsf(a0.z) * m0.z, fabsf(a0.w) * m0.w);
        pk.z = pack2(fabsf(a1.x) * m1.x, fabsf(a1.y) * m1.y);
        pk.w = pack2(fabsf(a1.z) * m1.z, fabsf(a1.w) * m1.w);
        int byte = (rl * 2048 + k * 2) ^ ((rl & 7) << 4);
        *(uint4*)((char*)weff + byte) = pk;
    }
    {
        int rl = tid >> 4;
        int k  = (tid & 15) * 8;
        const float* wr = Wahx + (m * NSL + rl) * NIN + k;
        float4 a0 = *(const float4*)wr;  float4 a1 = *(const float4*)(wr + 4);
        uint4 pk;
        pk.x = pack2(a0.x, a0.y); pk.y = pack2(a0.z, a0.w);
        pk.z = pack2(a1.x, a1.y); pk.w = pack2(a1.z, a1.w);
        int byte = (rl * 256 + k * 2) ^ ((rl & 7) << 4);
        *(uint4*)((char*)wahxs + byte) = pk;
    }
    if (tid < 128) {
        int k = tid * 8;
        const float* wr = Wyh + m * NREC + k;
        float4 a0 = *(const float4*)wr;  float4 a1 = *(const float4*)(wr + 4);
        uint4 pk;
        pk.x = pack2(a0.x, a0.y); pk.y = pack2(a0.z, a0.w);
        pk.z = pack2(a1.x, a1.y); pk.w = pack2(a1.z, a1.w);
        *(uint4*)((char*)wyhs + k * 2) = pk;
    }

    // per-thread state: (b_loc, nl)
    const int b_loc = tid >> 4;
    const int nl    = tid & 15;
    const int n_g   = m * NSL + nl;
    float ahv  = ah0[n_g];
    float bahv = bah[n_g];
    float byv  = by[m];

    // h(0) = retanh(ah0) -> hbuf slot 0, tag 0 (natural sign bits)
    {
        float th = tanhf(ahv);
        float h0 = th > 0.f ? th : 0.f;
        unsigned hb = f2bf(h0);
        unsigned nb = __shfl_down(hb, 1);
        if ((nl & 1) == 0) {
            unsigned w32 = hb | (nb << 16);
            int eidx = ((g * 2 + 0) * BPG + b_loc) * NREC + n_g;
            __hip_atomic_store((unsigned*)hbuf + (eidx >> 1), w32, __ATOMIC_RELAXED, SCOPE);
        }
    }
    __syncthreads();   // LDS slabs ready before use

    const int bcol = lane & 15;          // batch col for MFMA, also A row
    const int khi  = (lane >> 4) * 8;    // per-lane k offset within 32-chunk

    for (int t = 0; t <= T_; ++t) {
        // ---- prefetch x fragment (independent of h(t)) ----
        bf16x8 xf, axf;
        if (t < T_) {
            int i = w * 32 + khi;
            xf = *(const bf16x8*)(xb + ((size_t)(g * BPG + bcol) * T_ + t) * NIN + i);
            int byte = (bcol * 256 + i * 2) ^ ((bcol & 7) << 4);
            axf = *(const bf16x8*)((const char*)wahxs + byte);
        }

        // ---- poll-load h(t): per-chunk retry, tags self-certify ----
        const int slot = t & 1;
        const unsigned long long want = ((t >> 1) & 1) ? TAGMASK : 0ull;
        const unsigned long long* hq =
            (const unsigned long long*)(hbuf + ((g * 2 + slot) * BPG + bcol) * NREC);

        U16B u[8];
        unsigned pend = 0xFFu;           // per-lane pending chunk mask
        for (;;) {
            #pragma unroll
            for (int c = 0; c < 8; ++c) {
                if (pend & (1u << c)) {
                    int k = w * 256 + c * 32 + khi;
                    u[c].q[0] = __hip_atomic_load(hq + (k >> 2),     __ATOMIC_RELAXED, SCOPE);
                    u[c].q[1] = __hip_atomic_load(hq + (k >> 2) + 1, __ATOMIC_RELAXED, SCOPE);
                }
            }
            unsigned np = 0u;
            #pragma unroll
            for (int c = 0; c < 8; ++c) {
                if (pend & (1u << c)) {
                    unsigned long long d = ((u[c].q[0] ^ want) | (u[c].q[1] ^ want)) & TAGMASK;
                    np |= d ? (1u << c) : 0u;
                }
            }
            pend = np;
            if (!__any(pend != 0u)) break;
            __builtin_amdgcn_s_sleep(1);   // ~64cy backoff: don't hammer the LLC
        }
        bf16x8 bfrag[8];
        #pragma unroll
        for (int c = 0; c < 8; ++c) {
            u[c].q[0] &= ~TAGMASK;      // clear tags (real sign bits are 0)
            u[c].q[1] &= ~TAGMASK;
            bfrag[c] = u[c].s;
        }

        f32x4 acc = {0.f, 0.f, 0.f, 0.f};
        if (t < T_) {
            // two independent accumulators halve the serial MFMA dep chain
            f32x4 a0 = {0.f, 0.f, 0.f, 0.f};
            f32x4 a1 = {0.f, 0.f, 0.f, 0.f};
            a0 = __builtin_amdgcn_mfma_f32_16x16x32_bf16(axf, xf, a0, 0, 0, 0);
            #pragma unroll
            for (int c = 0; c < 4; ++c) {
                int k = w * 256 + c * 32 + khi;
                int byte = (bcol * 2048 + k * 2) ^ ((bcol & 7) << 4);
                bf16x8 af = *(const bf16x8*)((const char*)weff + byte);
                a0 = __builtin_amdgcn_mfma_f32_16x16x32_bf16(af, bfrag[c], a0, 0, 0, 0);
            }
            #pragma unroll
            for (int c = 4; c < 8; ++c) {
                int k = w * 256 + c * 32 + khi;
                int byte = (bcol * 2048 + k * 2) ^ ((bcol & 7) << 4);
                bf16x8 af = *(const bf16x8*)((const char*)weff + byte);
                a1 = __builtin_amdgcn_mfma_f32_16x16x32_bf16(af, bfrag[c], a1, 0, 0, 0);
            }
            acc = a0 + a1;
        }

        *(f32x4*)&red[w][0][lane][0] = acc;
        __syncthreads();

        if (t < T_) {
            // D mapping: col = lane&15 (=batch), row = (lane>>4)*4 + reg (=n-local)
            int src = ((nl >> 2) << 4) | b_loc;
            int reg = nl & 3;
            float r = red[0][0][src][reg] + red[1][0][src][reg]
                    + red[2][0][src][reg] + red[3][0][src][reg];
            ahv = 0.9f * ahv + DT * (r + bahv);
            float th = tanhf(ahv);
            float h  = th > 0.f ? th : 0.f;
            unsigned hb = f2bf(h);
            unsigned nb = __shfl_down(hb, 1);
            if ((nl & 1) == 0) {
                unsigned tagw = (unsigned)(((t + 1) >> 1) & 1) << 31;
                unsigned w32 = hb | (nb << 16) | tagw;
                int eidx = ((g * 2 + (slot ^ 1)) * BPG + b_loc) * NREC + n_g;
                __hip_atomic_store((unsigned*)hbuf + (eidx >> 1), w32, __ATOMIC_RELAXED, SCOPE);
            }
            // no ack, no flag: each word self-announces via its tag
        }

        // ---- y for output step t-1 (off the critical inter-WG chain) ----
        if (t >= 1) {
            f32x4 accy = {0.f, 0.f, 0.f, 0.f};
            #pragma unroll
            for (int c = 0; c < 8; ++c) {
                int k = w * 256 + c * 32 + khi;
                bf16x8 af = *(const bf16x8*)((const char*)wyhs + k * 2);
                accy = __builtin_amdgcn_mfma_f32_16x16x32_bf16(af, bfrag[c], accy, 0, 0, 0);
            }
            *(f32x4*)&red[w][1][lane][0] = accy;
            __syncthreads();
            if (tid < BPG) {
                float yv = red[0][1][tid][0] + red[1][1][tid][0]
                         + red[2][1][tid][0] + red[3][1][tid][0] + byv;
                __builtin_nontemporal_store(yv, &y[((size_t)(g * BPG + tid) * T_ + (t - 1)) * NOUT + m]);
            }
        } else {
            // t==0 has no y-phase barrier; order red[][0] reads before t=1 writes.
            __syncthreads();
        }
    }
}

extern "C" void kernel_launch(void* const* d_in, const int* in_sizes, int n_in,
                              void* d_out, int out_size, void* d_ws, size_t ws_size,
                              hipStream_t stream) {
    const float* x    = (const float*)d_in[0];
    const float* Wahx = (const float*)d_in[1];
    const float* Wahh = (const float*)d_in[2];
    const float* Wyh  = (const float*)d_in[3];
    const float* bah  = (const float*)d_in[4];
    const float* by   = (const float*)d_in[5];
    const float* ah0  = (const float*)d_in[6];
    const float* mask = (const float*)d_in[7];
    float* y = (float*)d_out;
    char* ws = (char*)d_ws;
    unsigned short* xb   = (unsigned short*)(ws + XB_OFF);
    unsigned short* hbuf = (unsigned short*)(ws + HBUF_OFF);

    (void)in_sizes; (void)n_in; (void)out_size; (void)ws_size;

    // poison hbuf: all tag bits = 1, so phase-0 consumers (t=0,1) cannot
    // false-accept before the first writes land.
    hipMemsetAsync(hbuf, 0xFF, HBUF_BYTES, stream);
    cast_x_kernel<<<dim3(2048), dim3(256), 0, stream>>>(x, xb, (B_ * T_ * NIN) / 4);
    rnn_main<<<dim3(GROUPS * MEMBERS), dim3(256), 0, stream>>>(
        Wahx, Wahh, Wyh, bah, by, ah0, mask, xb, hbuf, y);
}